// Round 22
// baseline (278.894 us; speedup 1.0000x reference)
//
#include <hip/hip_runtime.h>

#define N_NODES 20000
#define N_EDGES 320000
#define ET (N_EDGES + N_NODES)   // 340000 edges incl self-loops
#define F_IN 1024
#define HC 256                   // H*C for layers 1,2
#define NC 4

typedef unsigned short ushort_t;
typedef __attribute__((ext_vector_type(8))) short short8;
typedef __attribute__((ext_vector_type(4))) float f32x4;

// bf16 <-> f32 via bit ops (RTNE)
__device__ inline ushort_t f2bf(float f) {
    unsigned u = __float_as_uint(f);
    unsigned r = (u + 0x7fffu + ((u >> 16) & 1u)) >> 16;
    return (ushort_t)r;
}
__device__ inline float bf2f(ushort_t u) {
    return __uint_as_float(((unsigned)u) << 16);
}

// packed f32x2 -> bf16x2, HW RTNE
__device__ inline unsigned cvt_pk_bf16(float lo, float hi) {
    unsigned r;
    asm("v_cvt_pk_bf16_f32 %0, %1, %2" : "=v"(r) : "v"(lo), "v"(hi));
    return r;
}

#define GLOAD16(gp, lp) __builtin_amdgcn_global_load_lds( \
    (const __attribute__((address_space(1))) void*)(gp),  \
    (__attribute__((address_space(3))) void*)(lp), 16, 0, 0)

// ================= D1: w1 split (S1 blocks) || edge count (EB blocks) =================
__global__ void d1_split1_count(const float* __restrict__ w1, ushort_t* __restrict__ w1Th,
                                ushort_t* __restrict__ w1Tl,
                                const int* __restrict__ ei, int* __restrict__ counts) {
    const int S1 = F_IN * HC / 256;       // 1024
    int b = blockIdx.x;
    if (b < S1) {
        int idx = b * 256 + threadIdx.x;
        int k = idx / HC, n = idx - k * HC;
        float v = w1[idx];
        ushort_t h = f2bf(v);
        w1Th[(size_t)n * F_IN + k] = h;
        w1Tl[(size_t)n * F_IN + k] = f2bf(v - bf2f(h));
    } else {
        int e = (b - S1) * 256 + threadIdx.x;
        if (e < ET) {
            int dst = (e < N_EDGES) ? ei[N_EDGES + e] : (e - N_EDGES);
            atomicAdd(&counts[dst], 1);
        }
    }
}

// ================= D2: [aux: scan | w2 | w3] first, then gemm1(split-K) =================
// blocks [0]: scan; [1,257): w2; [257,321): w3; [NAUX, NAUX+nwgG): gemm1
#define NAUX 321
template<int GY>
__launch_bounds__(256)
__global__ void d2_gemm1_fused(const float* __restrict__ X,
                               const ushort_t* __restrict__ BTh, const ushort_t* __restrict__ BTl,
                               float* __restrict__ Cp0, float* __restrict__ Cp1,
                               int M, int K, int NT, int nwgG,
                               const int* __restrict__ counts, int* __restrict__ row_ptr,
                               int* __restrict__ cursor,
                               const float* __restrict__ w2, ushort_t* __restrict__ w2Th,
                               ushort_t* __restrict__ w2Tl,
                               const float* __restrict__ w3, ushort_t* __restrict__ w3Th,
                               ushort_t* __restrict__ w3Tl) {
    constexpr int BM = 128, BN = 64, SM = 64, SN = 32, MF = 4, NF = 2;
    __shared__ __align__(16) char smem[49152];

    const int bid = blockIdx.x;
    if (bid < NAUX) {
        if (bid == 0) {
            // ---- scan (256 threads) ----
            int* ssum = (int*)smem;
            int tt = threadIdx.x;
            const int per = (N_NODES + 255) / 256;     // 79
            int b0 = tt * per, e0 = min(b0 + per, N_NODES);
            int s = 0;
            for (int i = b0; i < e0; ++i) s += counts[i];
            ssum[tt] = s;
            __syncthreads();
            for (int o = 1; o < 256; o <<= 1) {
                int v = (tt >= o) ? ssum[tt - o] : 0;
                __syncthreads();
                ssum[tt] += v;
                __syncthreads();
            }
            int run = (tt == 0) ? 0 : ssum[tt - 1];
            for (int i = b0; i < e0; ++i) {
                row_ptr[i] = run;
                cursor[i]  = run;
                run += counts[i];
            }
            if (tt == 0) row_ptr[N_NODES] = ET;
        } else if (bid <= 256) {
            // ---- w2 split ----
            int idx = (bid - 1) * 256 + threadIdx.x;
            int k = idx / HC, n = idx - k * HC;
            float v = w2[idx];
            ushort_t h = f2bf(v);
            w2Th[(size_t)n * HC + k] = h;
            w2Tl[(size_t)n * HC + k] = f2bf(v - bf2f(h));
        } else {
            // ---- w3 split ----
            int idx = (bid - 257) * 256 + threadIdx.x;
            int k = idx / 64, n = idx - k * 64;
            float v = w3[idx];
            ushort_t h = f2bf(v);
            w3Th[(size_t)n * HC + k] = h;
            w3Tl[(size_t)n * HC + k] = f2bf(v - bf2f(h));
        }
        return;
    }

    // ---- gemm1 body (R18-proven: split-K, BK=64, reg-A cvt_pk, post-barrier prefetch) ----
    const int t = threadIdx.x, lane = t & 63, w = t >> 6;
    const int wm = w >> 1, wn = w & 1;
    const int nwg = nwgG;
    const int id = bid - NAUX;
    const int q = nwg >> 3, r = nwg & 7;
    const int xcd = id & 7, idx = id >> 3;
    const int logical = (xcd < r ? xcd * (q + 1) : r * (q + 1) + (xcd - r) * q) + idx;
    const int nwg_half = nwg >> 1;
    const int ks = logical / nwg_half;
    const int rem = logical - ks * nwg_half;
    const int bm = (rem / GY) * BM, bn = (rem % GY) * BN;
    const int kbase = ks * (K >> 1);
    float* Cp = ks ? Cp1 : Cp0;

    const int achk = lane & 3;
    const float* xRow[2]; int aoff[2];
    #pragma unroll
    for (int qq = 0; qq < 2; ++qq) {
        int arow = (w * 2 + qq) * 16 + (lane >> 2);
        int grow = min(bm + arow, M - 1);
        xRow[qq] = X + (size_t)grow * K + kbase + achk * 8;
        aoff[qq] = arow * 64 + ((achk ^ ((arow >> 1) & 3)) * 16);
    }
    const int gchunk = ((lane & 3) ^ ((lane >> 3) & 3)) * 16;
    const int brow = w * 16 + (lane >> 2);
    const size_t gB = (size_t)(bn + brow) * K * 2 + (size_t)kbase * 2 + gchunk;
    const int lB = w * 1024;

    const char* Bhb = (const char*)BTh;
    const char* Blb = (const char*)BTl;
    const int c16 = (lane >> 4);
    const int NTs = K >> 7;                        // (K/2)/64 tiles per half

    f32x4 acc[MF][NF];
    #pragma unroll
    for (int i = 0; i < MF; ++i)
        #pragma unroll
        for (int j = 0; j < NF; ++j) acc[i][j] = (f32x4){0.f, 0.f, 0.f, 0.f};

    float4 cur0[2][2], cur1[2][2], nxt0[2][2], nxt1[2][2];
    #pragma unroll
    for (int qq = 0; qq < 2; ++qq)
        #pragma unroll
        for (int kc = 0; kc < 2; ++kc) {
            cur0[qq][kc] = *(const float4*)(xRow[qq] + kc * 32);
            cur1[qq][kc] = *(const float4*)(xRow[qq] + kc * 32 + 4);
        }

    for (int ts = 0; ts < NTs; ++ts) {
        size_t kb = (size_t)ts * 128;
        #pragma unroll
        for (int kc = 0; kc < 2; ++kc) {
            GLOAD16(Bhb + gB + kb + kc * 64, smem + 32768 + kc * 4096 + lB);
            GLOAD16(Blb + gB + kb + kc * 64, smem + 40960 + kc * 4096 + lB);
        }
        #pragma unroll
        for (int qq = 0; qq < 2; ++qq)
            #pragma unroll
            for (int kc = 0; kc < 2; ++kc) {
                float vv[8] = {cur0[qq][kc].x, cur0[qq][kc].y, cur0[qq][kc].z, cur0[qq][kc].w,
                               cur1[qq][kc].x, cur1[qq][kc].y, cur1[qq][kc].z, cur1[qq][kc].w};
                unsigned hp[4], lp[4];
                #pragma unroll
                for (int j = 0; j < 4; ++j) {
                    unsigned h = cvt_pk_bf16(vv[2 * j], vv[2 * j + 1]);
                    float h0 = __uint_as_float(h << 16);
                    float h1 = __uint_as_float(h & 0xFFFF0000u);
                    hp[j] = h;
                    lp[j] = cvt_pk_bf16(vv[2 * j] - h0, vv[2 * j + 1] - h1);
                }
                *(uint4*)(smem + kc * 8192 + aoff[qq])         = make_uint4(hp[0], hp[1], hp[2], hp[3]);
                *(uint4*)(smem + 16384 + kc * 8192 + aoff[qq]) = make_uint4(lp[0], lp[1], lp[2], lp[3]);
            }
        __syncthreads();
        if (ts + 1 < NTs) {
            int ko = (ts + 1) * 64;
            #pragma unroll
            for (int qq = 0; qq < 2; ++qq)
                #pragma unroll
                for (int kc = 0; kc < 2; ++kc) {
                    nxt0[qq][kc] = *(const float4*)(xRow[qq] + ko + kc * 32);
                    nxt1[qq][kc] = *(const float4*)(xRow[qq] + ko + kc * 32 + 4);
                }
        }
        #pragma unroll
        for (int kc = 0; kc < 2; ++kc) {
            short8 afh[MF], afl[MF], bfh[NF], bfl[NF];
            #pragma unroll
            for (int i = 0; i < MF; ++i) {
                int row = wm * SM + i * 16 + (lane & 15);
                int off = row * 64 + ((c16 ^ ((row >> 1) & 3)) * 16);
                afh[i] = *(const short8*)(smem + kc * 8192 + off);
                afl[i] = *(const short8*)(smem + 16384 + kc * 8192 + off);
            }
            #pragma unroll
            for (int j = 0; j < NF; ++j) {
                int row = wn * SN + j * 16 + (lane & 15);
                int off = row * 64 + ((c16 ^ ((row >> 1) & 3)) * 16);
                bfh[j] = *(const short8*)(smem + 32768 + kc * 4096 + off);
                bfl[j] = *(const short8*)(smem + 40960 + kc * 4096 + off);
            }
            #pragma unroll
            for (int i = 0; i < MF; ++i)
                #pragma unroll
                for (int j = 0; j < NF; ++j) {
                    acc[i][j] = __builtin_amdgcn_mfma_f32_16x16x32_bf16(afh[i], bfh[j], acc[i][j], 0, 0, 0);
                    acc[i][j] = __builtin_amdgcn_mfma_f32_16x16x32_bf16(afh[i], bfl[j], acc[i][j], 0, 0, 0);
                    acc[i][j] = __builtin_amdgcn_mfma_f32_16x16x32_bf16(afl[i], bfh[j], acc[i][j], 0, 0, 0);
                }
        }
        __syncthreads();
        #pragma unroll
        for (int qq = 0; qq < 2; ++qq)
            #pragma unroll
            for (int kc = 0; kc < 2; ++kc) { cur0[qq][kc] = nxt0[qq][kc]; cur1[qq][kc] = nxt1[qq][kc]; }
    }
    #pragma unroll
    for (int i = 0; i < MF; ++i) {
        int rbase = bm + wm * SM + i * 16 + (lane >> 4) * 4;
        #pragma unroll
        for (int j = 0; j < NF; ++j) {
            int col = bn + wn * SN + j * 16 + (lane & 15);
            #pragma unroll
            for (int rr = 0; rr < 4; ++rr)
                if (rbase + rr < M) Cp[(size_t)(rbase + rr) * NT + col] = acc[i][j][rr];
        }
    }
}

// ================= D3: scatter (EB blocks) || reduce_al (5000 blocks) =================
__launch_bounds__(256)
__global__ void d3_scatter_reduce(const int* __restrict__ ei, int* __restrict__ cursor,
                                  int* __restrict__ col,
                                  float* __restrict__ B0, const float* __restrict__ Cp1,
                                  const float* __restrict__ as_w, const float* __restrict__ ad_w,
                                  float* __restrict__ als, float* __restrict__ ald) {
    const int EB = (ET + 255) / 256;
    int b = blockIdx.x;
    if (b < EB) {
        int e = b * 256 + threadIdx.x;
        if (e >= ET) return;
        int src, dst;
        if (e < N_EDGES) { src = ei[e]; dst = ei[N_EDGES + e]; }
        else             { src = dst = e - N_EDGES; }
        int pos = atomicAdd(&cursor[dst], 1);
        col[pos] = src;
        return;
    }
    int lane = threadIdx.x & 63, w = threadIdx.x >> 6;
    int row = (b - EB) * 4 + w;
    if (row >= N_NODES) return;
    size_t base = (size_t)row * HC + lane * 4;
    float4 p0 = *(const float4*)&B0[base];
    float4 p1 = *(const float4*)&Cp1[base];
    float4 s = make_float4(p0.x + p1.x, p0.y + p1.y, p0.z + p1.z, p0.w + p1.w);
    *(float4*)&B0[base] = s;
    int head = lane >> 4;
    int cw = (lane & 15) * 4;
    float ps = s.x * as_w[head * 64 + cw + 0] + s.y * as_w[head * 64 + cw + 1]
             + s.z * as_w[head * 64 + cw + 2] + s.w * as_w[head * 64 + cw + 3];
    float pd = s.x * ad_w[head * 64 + cw + 0] + s.y * ad_w[head * 64 + cw + 1]
             + s.z * ad_w[head * 64 + cw + 2] + s.w * ad_w[head * 64 + cw + 3];
    #pragma unroll
    for (int o = 1; o < 16; o <<= 1) {
        ps += __shfl_xor(ps, o, 64);
        pd += __shfl_xor(pd, o, 64);
    }
    if ((lane & 15) == 0) {
        als[row * 4 + head] = ps;
        ald[row * 4 + head] = pd;
    }
}

// ======== fused attention-logit epilogue (used by gemm_mfma) ========
#define AL_EPILOGUE()                                                              \
    {                                                                              \
        float asv[NF], adv[NF];                                                    \
        _Pragma("unroll")                                                          \
        for (int j = 0; j < NF; ++j) {                                             \
            int col = bn + wn * SN + j * 16 + (lane & 15);                         \
            asv[j] = as_w[col];                                                    \
            adv[j] = ad_w[col];                                                    \
        }                                                                          \
        float* s_as = (float*)smem;          /* [2][BM] */                         \
        float* s_ad = (float*)smem + 2 * BM;                                       \
        _Pragma("unroll")                                                          \
        for (int i = 0; i < MF; ++i) {                                             \
            _Pragma("unroll")                                                      \
            for (int rr = 0; rr < 4; ++rr) {                                       \
                float ps = 0.f, pd = 0.f;                                          \
                _Pragma("unroll")                                                  \
                for (int j = 0; j < NF; ++j) {                                     \
                    ps += acc[i][j][rr] * asv[j];                                  \
                    pd += acc[i][j][rr] * adv[j];                                  \
                }                                                                  \
                _Pragma("unroll")                                                  \
                for (int o = 1; o < 16; o <<= 1) {                                 \
                    ps += __shfl_xor(ps, o, 64);                                   \
                    pd += __shfl_xor(pd, o, 64);                                   \
                }                                                                  \
                if ((lane & 15) == 0) {                                            \
                    int rl = wm * SM + i * 16 + (lane >> 4) * 4 + rr;              \
                    s_as[wn * BM + rl] = ps;                                       \
                    s_ad[wn * BM + rl] = pd;                                       \
                }                                                                  \
            }                                                                      \
        }                                                                          \
        __syncthreads();                                                           \
        if (t < BM) {                                                              \
            int row = bm + t;                                                      \
            if (row < M) {                                                         \
                int hb = bn >> 6;                                                  \
                als[row * H + hb] = s_as[t] + s_as[BM + t];                        \
                ald[row * H + hb] = s_ad[t] + s_ad[BM + t];                        \
            }                                                                      \
        }                                                                          \
    }

// ---------------- split-bf16 MFMA GEMM (bf16 A), BK=64, fused al ----------------
template<int BMT, int GY, int H>
__launch_bounds__(256)
__global__ void gemm_mfma(const ushort_t* __restrict__ Ah, const ushort_t* __restrict__ Al,
                          const ushort_t* __restrict__ BTh, const ushort_t* __restrict__ BTl,
                          float* __restrict__ C, const float* __restrict__ as_w,
                          const float* __restrict__ ad_w, float* __restrict__ als,
                          float* __restrict__ ald, int M, int K, int NT) {
    constexpr int BM = BMT, BN = 64, SM = BM / 2, SN = 32, MF = SM / 16, NF = 2;
    constexpr int AQ = BM / 64;
    constexpr int ASZ = BM * 64;
    __shared__ __align__(16) char smem[4 * ASZ + 16384];

    const int t = threadIdx.x, lane = t & 63, w = t >> 6;
    const int wm = w >> 1, wn = w & 1;
    const int nwg = gridDim.x;
    const int id = blockIdx.x;
    const int q = nwg >> 3, r = nwg & 7;
    const int xcd = id & 7, idx = id >> 3;
    const int logical = (xcd < r ? xcd * (q + 1) : r * (q + 1) + (xcd - r) * q) + idx;
    const int bm = (logical / GY) * BM, bn = (logical % GY) * BN;
    const int gchunk = ((lane & 3) ^ ((lane >> 3) & 3)) * 16;

    size_t gA[AQ]; int lA[AQ];
    #pragma unroll
    for (int qq = 0; qq < AQ; ++qq) {
        int inst = w * AQ + qq;
        int arow = inst * 16 + (lane >> 2);
        int grow = min(bm + arow, M - 1);
        gA[qq] = (size_t)grow * K * 2 + gchunk;
        lA[qq] = inst * 1024;
    }
    const int brow = w * 16 + (lane >> 2);
    const size_t gB = (size_t)(bn + brow) * K * 2 + gchunk;
    const int lB = w * 1024;

    const char* Ahb = (const char*)Ah;
    const char* Alb = (const char*)Al;
    const char* Bhb = (const char*)BTh;
    const char* Blb = (const char*)BTl;
    const int c16 = (lane >> 4);
    const int NTs = K / 64;

    f32x4 acc[MF][NF];
    #pragma unroll
    for (int i = 0; i < MF; ++i)
        #pragma unroll
        for (int j = 0; j < NF; ++j) acc[i][j] = (f32x4){0.f, 0.f, 0.f, 0.f};

    for (int ts = 0; ts < NTs; ++ts) {
        size_t kb = (size_t)ts * 128;
        #pragma unroll
        for (int kc = 0; kc < 2; ++kc) {
            #pragma unroll
            for (int qq = 0; qq < AQ; ++qq) {
                GLOAD16(Ahb + gA[qq] + kb + kc * 64, smem + kc * ASZ + lA[qq]);
                GLOAD16(Alb + gA[qq] + kb + kc * 64, smem + 2 * ASZ + kc * ASZ + lA[qq]);
            }
            GLOAD16(Bhb + gB + kb + kc * 64, smem + 4 * ASZ + kc * 4096 + lB);
            GLOAD16(Blb + gB + kb + kc * 64, smem + 4 * ASZ + 8192 + kc * 4096 + lB);
        }
        __syncthreads();
        #pragma unroll
        for (int kc = 0; kc < 2; ++kc) {
            short8 afh[MF], afl[MF], bfh[NF], bfl[NF];
            #pragma unroll
            for (int i = 0; i < MF; ++i) {
                int row = wm * SM + i * 16 + (lane & 15);
                int off = row * 64 + ((c16 ^ ((row >> 1) & 3)) * 16);
                afh[i] = *(const short8*)(smem + kc * ASZ + off);
                afl[i] = *(const short8*)(smem + 2 * ASZ + kc * ASZ + off);
            }
            #pragma unroll
            for (int j = 0; j < NF; ++j) {
                int row = wn * SN + j * 16 + (lane & 15);
                int off = row * 64 + ((c16 ^ ((row >> 1) & 3)) * 16);
                bfh[j] = *(const short8*)(smem + 4 * ASZ + kc * 4096 + off);
                bfl[j] = *(const short8*)(smem + 4 * ASZ + 8192 + kc * 4096 + off);
            }
            #pragma unroll
            for (int i = 0; i < MF; ++i)
                #pragma unroll
                for (int j = 0; j < NF; ++j) {
                    acc[i][j] = __builtin_amdgcn_mfma_f32_16x16x32_bf16(afh[i], bfh[j], acc[i][j], 0, 0, 0);
                    acc[i][j] = __builtin_amdgcn_mfma_f32_16x16x32_bf16(afh[i], bfl[j], acc[i][j], 0, 0, 0);
                    acc[i][j] = __builtin_amdgcn_mfma_f32_16x16x32_bf16(afl[i], bfh[j], acc[i][j], 0, 0, 0);
                }
        }
        __syncthreads();
    }
    #pragma unroll
    for (int i = 0; i < MF; ++i) {
        int rbase = bm + wm * SM + i * 16 + (lane >> 4) * 4;
        #pragma unroll
        for (int j = 0; j < NF; ++j) {
            int col = bn + wn * SN + j * 16 + (lane & 15);
            #pragma unroll
            for (int rr = 0; rr < 4; ++rr)
                if (rbase + rr < M) C[(size_t)(rbase + rr) * NT + col] = acc[i][j][rr];
        }
    }
    AL_EPILOGUE()
}

// ---------------- agg v6: fused per-head softmax + channel-sliced gather ----------------
template<int CT, int CW, int H, bool RELU, bool SPLIT, bool CLS>
__launch_bounds__(256)
__global__ void agg_v6(const float* __restrict__ h, const float* __restrict__ als,
                       const float* __restrict__ ald,
                       const int* __restrict__ row_ptr, const int* __restrict__ col,
                       const float* __restrict__ bias,
                       ushort_t* __restrict__ oh, ushort_t* __restrict__ ol,
                       float* __restrict__ of,
                       const float* __restrict__ wc, const float* __restrict__ bc,
                       float* __restrict__ cls_out) {
    constexpr int NS  = CT / CW;
    constexpr int LPT = CW / 4;
    constexpr int TPW = 64 / LPT;
    static_assert(NS == H, "slice==head mapping");
    __shared__ int   s_src[4][64];
    __shared__ float s_alp[4][64];
    const int nwg = gridDim.x;
    const int q = nwg >> 3;
    int id = blockIdx.x;
    int logical = (id & 7) * q + (id >> 3);
    int slice = logical / (N_NODES / 4);
    int g = logical - slice * (N_NODES / 4);
    int lane = threadIdx.x & 63, w = threadIdx.x >> 6;
    int dst = g * 4 + w;
    int beg = row_ptr[dst], deg = row_ptr[dst + 1] - beg;
    int team = lane / LPT;
    int cc = (lane & (LPT - 1)) * 4;

    const int*   colP = col + beg;
    const float* hS   = h + slice * CW + cc;
    float ad = ald[dst * H + slice];

    // ---- pass A: per-head softmax stats ----
    float m = -1e30f, den = 0.f;
    for (int base = 0; base < deg; base += 64) {
        int i = base + lane;
        if (i < deg) {
            float e = als[colP[i] * H + slice] + ad;
            e = (e > 0.f) ? e : 0.2f * e;
            float nm = fmaxf(m, e);
            den = den * __expf(m - nm) + __expf(e - nm);
            m = nm;
        }
    }
    #pragma unroll
    for (int off = 1; off < 64; off <<= 1) {
        float mo = __shfl_xor(m, off, 64);
        float dn = __shfl_xor(den, off, 64);
        float nm = fmaxf(m, mo);
        den = den * __expf(m - nm) + dn * __expf(mo - nm);
        m = nm;
    }
    float rden = 1.f / (den + 1e-16f);

    // ---- pass B: alpha inline to LDS, 4-deep team gather ----
    float4 a0v = make_float4(0.f, 0.f, 0.f, 0.f);
    float4 a1v = make_float4(0.f, 0.f, 0.f, 0.f);
    float4 a2v = make_float4(0.f, 0.f, 0.f, 0.f);
    float4 a3v = make_float4(0.f, 0.f, 0.f, 0.f);
    for (int base = 0; base < deg; base += 64) {
        int cnt = min(64, deg - base);
        if (lane < cnt) {
            int src = colP[base + lane];
            s_src[w][lane] = src;
            float e = als[src * H + slice] + ad;
            e = (e > 0.f) ? e : 0.2f * e;
            s_alp[w][lane] = __expf(e - m) * rden;
        }
        int i = team;
        for (; i + 3 * TPW < cnt; i += 4 * TPW) {
            int   s0 = s_src[w][i],           s1 = s_src[w][i + TPW];
            int   s2 = s_src[w][i + 2 * TPW], s3 = s_src[w][i + 3 * TPW];
            float a0 = s_alp[w][i],           a1 = s_alp[w][i + TPW];
            float a2 = s_alp[w][i + 2 * TPW], a3 = s_alp[w][i + 3 * TPW];
            float4 h0 = *(const float4*)&hS[s0 * CT];
            float4 h1 = *(const float4*)&hS[s1 * CT];
            float4 h2 = *(const float4*)&hS[s2 * CT];
            float4 h3 = *(const float4*)&hS[s3 * CT];
            a0v.x += a0 * h0.x; a0v.y += a0 * h0.y; a0v.z += a0 * h0.z; a0v.w += a0 * h0.w;
            a1v.x += a1 * h1.x; a1v.y += a1 * h1.y; a1v.z += a1 * h1.z; a1v.w += a1 * h1.w;
            a2v.x += a2 * h2.x; a2v.y += a2 * h2.y; a2v.z += a2 * h2.z; a2v.w += a2 * h2.w;
            a3v.x += a3 * h3.x; a3v.y += a3 * h3.y; a3v.z += a3 * h3.z; a3v.w += a3 * h3.w;
        }
        for (; i < cnt; i += TPW) {
            int   s0 = s_src[w][i];
            float a0 = s_alp[w][i];
            float4 h0 = *(const float4*)&hS[s0 * CT];
            a0v.x += a0 * h0.x; a0v.y += a0 * h0.y; a0v.z += a0 * h0.z; a0v.w += a0 * h0.w;
        }
    }
    float4 acc = make_float4((a0v.x + a1v.x) + (a2v.x + a3v.x),
                             (a0v.y + a1v.y) + (a2v.y + a3v.y),
                             (a0v.z + a1v.z) + (a2v.z + a3v.z),
                             (a0v.w + a1v.w) + (a2v.w + a3v.w));
    #pragma unroll
    for (int off = LPT; off < 64; off <<= 1) {
        acc.x += __shfl_xor(acc.x, off, 64);
        acc.y += __shfl_xor(acc.y, off, 64);
        acc.z += __shfl_xor(acc.z, off, 64);
        acc.w += __shfl_xor(acc.w, off, 64);
    }
    if (team == 0) {
        int ch = slice * CW + cc;
        float4 bv = *(const float4*)&bias[ch];
        float v0 = acc.x + bv.x, v1 = acc.y + bv.y, v2 = acc.z + bv.z, v3 = acc.w + bv.w;
        if (RELU) {
            v0 = fmaxf(v0, 0.f); v1 = fmaxf(v1, 0.f);
            v2 = fmaxf(v2, 0.f); v3 = fmaxf(v3, 0.f);
        }
        if (CLS) {
            float ps[NC];
            #pragma unroll
            for (int k = 0; k < NC; ++k)
                ps[k] = v0 * wc[(cc + 0) * NC + k] + v1 * wc[(cc + 1) * NC + k]
                      + v2 * wc[(cc + 2) * NC + k] + v3 * wc[(cc + 3) * NC + k];
            #pragma unroll
            for (int o = 1; o < 16; o <<= 1)
                #pragma unroll
                for (int k = 0; k < NC; ++k) ps[k] += __shfl_xor(ps[k], o, 64);
            if (lane == 0) {
                #pragma unroll
                for (int k = 0; k < NC; ++k) cls_out[(size_t)dst * NC + k] = ps[k] + bc[k];
            }
        } else {
            size_t idx = (size_t)dst * CT + ch;
            if (SPLIT) {
                ushort4 h4, l4;
                h4.x = f2bf(v0); l4.x = f2bf(v0 - bf2f(h4.x));
                h4.y = f2bf(v1); l4.y = f2bf(v1 - bf2f(h4.y));
                h4.z = f2bf(v2); l4.z = f2bf(v2 - bf2f(h4.z));
                h4.w = f2bf(v3); l4.w = f2bf(v3 - bf2f(h4.w));
                *(ushort4*)&oh[idx] = h4;
                *(ushort4*)&ol[idx] = l4;
            } else {
                *(float4*)&of[idx] = make_float4(v0, v1, v2, v3);
            }
        }
    }
}

extern "C" void kernel_launch(void* const* d_in, const int* in_sizes, int n_in,
                              void* d_out, int out_size, void* d_ws, size_t ws_size,
                              hipStream_t stream) {
    const float* x   = (const float*)d_in[0];
    const int*   ei  = (const int*)d_in[1];
    const float* w1  = (const float*)d_in[2];
    const float* as1 = (const float*)d_in[3];
    const float* ad1 = (const float*)d_in[4];
    const float* b1  = (const float*)d_in[5];
    const float* w2  = (const float*)d_in[6];
    const float* as2 = (const float*)d_in[7];
    const float* ad2 = (const float*)d_in[8];
    const float* b2  = (const float*)d_in[9];
    const float* w3  = (const float*)d_in[10];
    const float* as3 = (const float*)d_in[11];
    const float* ad3 = (const float*)d_in[12];
    const float* b3  = (const float*)d_in[13];
    const float* wc  = (const float*)d_in[14];
    const float* bc  = (const float*)d_in[15];
    float* out = (float*)d_out;

    char* ws = (char*)d_ws;
    size_t off = 0;
    auto alloc = [&](size_t bytes) -> char* {
        char* p = ws + off;
        off = (off + bytes + 255) & ~(size_t)255;
        return p;
    };

    int* counts  = (int*)alloc(N_NODES * 4);
    int* cursor  = (int*)alloc(N_NODES * 4);
    int* row_ptr = (int*)alloc((N_NODES + 1) * 4);
    int* colidx  = (int*)alloc(ET * 4);
    float* als   = (float*)alloc(N_NODES * 4 * 4);
    float* ald   = (float*)alloc(N_NODES * 4 * 4);
    float* B0    = (float*)alloc((size_t)N_NODES * HC * 4);
    float* Cp1   = (float*)alloc((size_t)N_NODES * HC * 4);

    ushort_t* w1Th = (ushort_t*)alloc((size_t)F_IN * HC * 2);
    ushort_t* w1Tl = (ushort_t*)alloc((size_t)F_IN * HC * 2);
    ushort_t* w2Th = (ushort_t*)alloc((size_t)HC * HC * 2);
    ushort_t* w2Tl = (ushort_t*)alloc((size_t)HC * HC * 2);
    ushort_t* w3Th = (ushort_t*)alloc((size_t)HC * 64 * 2);
    ushort_t* w3Tl = (ushort_t*)alloc((size_t)HC * 64 * 2);
    ushort_t* B1h  = (ushort_t*)alloc((size_t)N_NODES * HC * 2);
    ushort_t* B1l  = (ushort_t*)alloc((size_t)N_NODES * HC * 2);

    const int EB = (ET + 255) / 256;                         // 1329
    const int S1 = F_IN * HC / 256;                          // 1024
    const int nwg128 = ((N_NODES + 127) / 128) * (HC / 64);  // 628
    const int nwgG = 2 * nwg128;                             // 1256
    const int nblk_dst = N_NODES / 4;                        // 5000

    // ---- D1: w1 split || edge count ----
    hipMemsetAsync(counts, 0, N_NODES * sizeof(int), stream);
    d1_split1_count<<<S1 + EB, 256, 0, stream>>>(w1, w1Th, w1Tl, ei, counts);
    // ---- D2: [scan | w2 | w3] first, then gemm1 ----
    d2_gemm1_fused<4><<<NAUX + nwgG, 256, 0, stream>>>(
        x, w1Th, w1Tl, B0, Cp1, N_NODES, F_IN, HC, nwgG,
        counts, row_ptr, cursor, w2, w2Th, w2Tl, w3, w3Th, w3Tl);
    // ---- D3: scatter || reduce+al ----
    d3_scatter_reduce<<<EB + nblk_dst, 256, 0, stream>>>(
        ei, cursor, colidx, B0, Cp1, as1, ad1, als, ald);
    // ---- layer 1 agg ----
    agg_v6<256, 64, 4, true, true, false><<<4 * nblk_dst, 256, 0, stream>>>(
        B0, als, ald, row_ptr, colidx, b1, B1h, B1l, nullptr, nullptr, nullptr, nullptr);
    // ---- layer 2 ----
    gemm_mfma<128, 4, 4><<<nwg128, 256, 0, stream>>>(B1h, B1l, w2Th, w2Tl, B0, as2, ad2,
                                                     als, ald, N_NODES, HC, HC);
    agg_v6<256, 64, 4, true, true, false><<<4 * nblk_dst, 256, 0, stream>>>(
        B0, als, ald, row_ptr, colidx, b2, B1h, B1l, nullptr, nullptr, nullptr, nullptr);
    // ---- layer 3 (H=1, C=64) + fused classifier ----
    const int nwg3 = (N_NODES + 63) / 64;                    // 313
    gemm_mfma<64, 1, 1><<<nwg3, 256, 0, stream>>>(B1h, B1l, w3Th, w3Tl, B0, as3, ad3,
                                                  als, ald, N_NODES, HC, 64);
    agg_v6<64, 64, 1, false, false, true><<<nblk_dst, 256, 0, stream>>>(
        B0, als, ald, row_ptr, colidx, b3, nullptr, nullptr, nullptr, wc, bc, out);
}

// Round 23
// 277.393 us; speedup vs baseline: 1.0054x; 1.0054x over previous
//
#include <hip/hip_runtime.h>

#define N_NODES 20000
#define N_EDGES 320000
#define ET (N_EDGES + N_NODES)   // 340000 edges incl self-loops
#define F_IN 1024
#define HC 256                   // H*C for layers 1,2
#define NC 4

typedef unsigned short ushort_t;
typedef __attribute__((ext_vector_type(8))) short short8;
typedef __attribute__((ext_vector_type(4))) float f32x4;

// bf16 <-> f32 via bit ops (RTNE)
__device__ inline ushort_t f2bf(float f) {
    unsigned u = __float_as_uint(f);
    unsigned r = (u + 0x7fffu + ((u >> 16) & 1u)) >> 16;
    return (ushort_t)r;
}
__device__ inline float bf2f(ushort_t u) {
    return __uint_as_float(((unsigned)u) << 16);
}

// packed f32x2 -> bf16x2, HW RTNE
__device__ inline unsigned cvt_pk_bf16(float lo, float hi) {
    unsigned r;
    asm("v_cvt_pk_bf16_f32 %0, %1, %2" : "=v"(r) : "v"(lo), "v"(hi));
    return r;
}

#define GLOAD16(gp, lp) __builtin_amdgcn_global_load_lds( \
    (const __attribute__((address_space(1))) void*)(gp),  \
    (__attribute__((address_space(3))) void*)(lp), 16, 0, 0)

// ---------------- prep: edge-count + 3 weight splits in one kernel (R18-proven) ----------------
__global__ void prep_kernel(const int* __restrict__ ei, int* __restrict__ counts,
                            const float* __restrict__ w1, ushort_t* __restrict__ w1Th,
                            ushort_t* __restrict__ w1Tl,
                            const float* __restrict__ w2, ushort_t* __restrict__ w2Th,
                            ushort_t* __restrict__ w2Tl,
                            const float* __restrict__ w3, ushort_t* __restrict__ w3Th,
                            ushort_t* __restrict__ w3Tl) {
    const int EB = (ET + 255) / 256;      // 1329
    const int S1 = F_IN * HC / 256;       // 1024
    const int S2 = HC * HC / 256;         // 256
    int b = blockIdx.x;
    if (b < EB) {
        int e = b * 256 + threadIdx.x;
        if (e < ET) {
            int dst = (e < N_EDGES) ? ei[N_EDGES + e] : (e - N_EDGES);
            atomicAdd(&counts[dst], 1);
        }
    } else if (b < EB + S1) {
        int idx = (b - EB) * 256 + threadIdx.x;
        int k = idx / HC, n = idx - k * HC;
        float v = w1[idx];
        ushort_t h = f2bf(v);
        w1Th[(size_t)n * F_IN + k] = h;
        w1Tl[(size_t)n * F_IN + k] = f2bf(v - bf2f(h));
    } else if (b < EB + S1 + S2) {
        int idx = (b - EB - S1) * 256 + threadIdx.x;
        int k = idx / HC, n = idx - k * HC;
        float v = w2[idx];
        ushort_t h = f2bf(v);
        w2Th[(size_t)n * HC + k] = h;
        w2Tl[(size_t)n * HC + k] = f2bf(v - bf2f(h));
    } else {
        int idx = (b - EB - S1 - S2) * 256 + threadIdx.x;
        int k = idx / 64, n = idx - k * 64;
        float v = w3[idx];
        ushort_t h = f2bf(v);
        w3Th[(size_t)n * HC + k] = h;
        w3Tl[(size_t)n * HC + k] = f2bf(v - bf2f(h));
    }
}

__global__ void scan_kernel(const int* __restrict__ counts, int* __restrict__ row_ptr,
                            int* __restrict__ cursor) {
    __shared__ int sums[1024];
    int t = threadIdx.x;
    const int per = (N_NODES + 1023) / 1024;
    int b = t * per;
    int e = min(b + per, N_NODES);
    int s = 0;
    for (int i = b; i < e; ++i) s += counts[i];
    sums[t] = s;
    __syncthreads();
    for (int off = 1; off < 1024; off <<= 1) {
        int v = (t >= off) ? sums[t - off] : 0;
        __syncthreads();
        sums[t] += v;
        __syncthreads();
    }
    int run = (t == 0) ? 0 : sums[t - 1];
    for (int i = b; i < e; ++i) {
        row_ptr[i] = run;
        cursor[i]  = run;
        run += counts[i];
    }
    if (t == 0) row_ptr[N_NODES] = ET;
}

// ---------------- GEMM1 standalone (R18-proven): fp32 A, cvt_pk split, BK=64, split-K ----------------
template<int GY>
__launch_bounds__(256)
__global__ void gemm_f32a_ks(const float* __restrict__ X,
                             const ushort_t* __restrict__ BTh, const ushort_t* __restrict__ BTl,
                             float* __restrict__ Cp0, float* __restrict__ Cp1,
                             int M, int K, int NT) {
    constexpr int BM = 128, BN = 64, SM = 64, SN = 32, MF = 4, NF = 2;
    __shared__ __align__(16) char smem[49152];

    const int t = threadIdx.x, lane = t & 63, w = t >> 6;
    const int wm = w >> 1, wn = w & 1;
    const int nwg = gridDim.x;
    const int id = blockIdx.x;
    const int q = nwg >> 3, r = nwg & 7;
    const int xcd = id & 7, idx = id >> 3;
    const int logical = (xcd < r ? xcd * (q + 1) : r * (q + 1) + (xcd - r) * q) + idx;
    const int nwg_half = nwg >> 1;
    const int ks = logical / nwg_half;
    const int rem = logical - ks * nwg_half;
    const int bm = (rem / GY) * BM, bn = (rem % GY) * BN;
    const int kbase = ks * (K >> 1);
    float* Cp = ks ? Cp1 : Cp0;

    const int achk = lane & 3;
    const float* xRow[2]; int aoff[2];
    #pragma unroll
    for (int qq = 0; qq < 2; ++qq) {
        int arow = (w * 2 + qq) * 16 + (lane >> 2);
        int grow = min(bm + arow, M - 1);
        xRow[qq] = X + (size_t)grow * K + kbase + achk * 8;
        aoff[qq] = arow * 64 + ((achk ^ ((arow >> 1) & 3)) * 16);
    }
    const int gchunk = ((lane & 3) ^ ((lane >> 3) & 3)) * 16;
    const int brow = w * 16 + (lane >> 2);
    const size_t gB = (size_t)(bn + brow) * K * 2 + (size_t)kbase * 2 + gchunk;
    const int lB = w * 1024;

    const char* Bhb = (const char*)BTh;
    const char* Blb = (const char*)BTl;
    const int c16 = (lane >> 4);
    const int NTs = K >> 7;                        // (K/2)/64 tiles per half

    f32x4 acc[MF][NF];
    #pragma unroll
    for (int i = 0; i < MF; ++i)
        #pragma unroll
        for (int j = 0; j < NF; ++j) acc[i][j] = (f32x4){0.f, 0.f, 0.f, 0.f};

    float4 cur0[2][2], cur1[2][2], nxt0[2][2], nxt1[2][2];
    #pragma unroll
    for (int qq = 0; qq < 2; ++qq)
        #pragma unroll
        for (int kc = 0; kc < 2; ++kc) {
            cur0[qq][kc] = *(const float4*)(xRow[qq] + kc * 32);
            cur1[qq][kc] = *(const float4*)(xRow[qq] + kc * 32 + 4);
        }

    for (int ts = 0; ts < NTs; ++ts) {
        size_t kb = (size_t)ts * 128;
        #pragma unroll
        for (int kc = 0; kc < 2; ++kc) {
            GLOAD16(Bhb + gB + kb + kc * 64, smem + 32768 + kc * 4096 + lB);
            GLOAD16(Blb + gB + kb + kc * 64, smem + 40960 + kc * 4096 + lB);
        }
        #pragma unroll
        for (int qq = 0; qq < 2; ++qq)
            #pragma unroll
            for (int kc = 0; kc < 2; ++kc) {
                float vv[8] = {cur0[qq][kc].x, cur0[qq][kc].y, cur0[qq][kc].z, cur0[qq][kc].w,
                               cur1[qq][kc].x, cur1[qq][kc].y, cur1[qq][kc].z, cur1[qq][kc].w};
                unsigned hp[4], lp[4];
                #pragma unroll
                for (int j = 0; j < 4; ++j) {
                    unsigned h = cvt_pk_bf16(vv[2 * j], vv[2 * j + 1]);
                    float h0 = __uint_as_float(h << 16);
                    float h1 = __uint_as_float(h & 0xFFFF0000u);
                    hp[j] = h;
                    lp[j] = cvt_pk_bf16(vv[2 * j] - h0, vv[2 * j + 1] - h1);
                }
                *(uint4*)(smem + kc * 8192 + aoff[qq])         = make_uint4(hp[0], hp[1], hp[2], hp[3]);
                *(uint4*)(smem + 16384 + kc * 8192 + aoff[qq]) = make_uint4(lp[0], lp[1], lp[2], lp[3]);
            }
        __syncthreads();
        if (ts + 1 < NTs) {
            int ko = (ts + 1) * 64;
            #pragma unroll
            for (int qq = 0; qq < 2; ++qq)
                #pragma unroll
                for (int kc = 0; kc < 2; ++kc) {
                    nxt0[qq][kc] = *(const float4*)(xRow[qq] + ko + kc * 32);
                    nxt1[qq][kc] = *(const float4*)(xRow[qq] + ko + kc * 32 + 4);
                }
        }
        #pragma unroll
        for (int kc = 0; kc < 2; ++kc) {
            short8 afh[MF], afl[MF], bfh[NF], bfl[NF];
            #pragma unroll
            for (int i = 0; i < MF; ++i) {
                int row = wm * SM + i * 16 + (lane & 15);
                int off = row * 64 + ((c16 ^ ((row >> 1) & 3)) * 16);
                afh[i] = *(const short8*)(smem + kc * 8192 + off);
                afl[i] = *(const short8*)(smem + 16384 + kc * 8192 + off);
            }
            #pragma unroll
            for (int j = 0; j < NF; ++j) {
                int row = wn * SN + j * 16 + (lane & 15);
                int off = row * 64 + ((c16 ^ ((row >> 1) & 3)) * 16);
                bfh[j] = *(const short8*)(smem + 32768 + kc * 4096 + off);
                bfl[j] = *(const short8*)(smem + 40960 + kc * 4096 + off);
            }
            #pragma unroll
            for (int i = 0; i < MF; ++i)
                #pragma unroll
                for (int j = 0; j < NF; ++j) {
                    acc[i][j] = __builtin_amdgcn_mfma_f32_16x16x32_bf16(afh[i], bfh[j], acc[i][j], 0, 0, 0);
                    acc[i][j] = __builtin_amdgcn_mfma_f32_16x16x32_bf16(afh[i], bfl[j], acc[i][j], 0, 0, 0);
                    acc[i][j] = __builtin_amdgcn_mfma_f32_16x16x32_bf16(afl[i], bfh[j], acc[i][j], 0, 0, 0);
                }
        }
        __syncthreads();
        #pragma unroll
        for (int qq = 0; qq < 2; ++qq)
            #pragma unroll
            for (int kc = 0; kc < 2; ++kc) { cur0[qq][kc] = nxt0[qq][kc]; cur1[qq][kc] = nxt1[qq][kc]; }
    }
    #pragma unroll
    for (int i = 0; i < MF; ++i) {
        int rbase = bm + wm * SM + i * 16 + (lane >> 4) * 4;
        #pragma unroll
        for (int j = 0; j < NF; ++j) {
            int col = bn + wn * SN + j * 16 + (lane & 15);
            #pragma unroll
            for (int rr = 0; rr < 4; ++rr)
                if (rbase + rr < M) Cp[(size_t)(rbase + rr) * NT + col] = acc[i][j][rr];
        }
    }
}

// ================= D3: scatter (EB blocks) || reduce_al (5000 blocks) (R21-proven) =================
__launch_bounds__(256)
__global__ void d3_scatter_reduce(const int* __restrict__ ei, int* __restrict__ cursor,
                                  int* __restrict__ col,
                                  float* __restrict__ B0, const float* __restrict__ Cp1,
                                  const float* __restrict__ as_w, const float* __restrict__ ad_w,
                                  float* __restrict__ als, float* __restrict__ ald) {
    const int EB = (ET + 255) / 256;
    int b = blockIdx.x;
    if (b < EB) {
        int e = b * 256 + threadIdx.x;
        if (e >= ET) return;
        int src, dst;
        if (e < N_EDGES) { src = ei[e]; dst = ei[N_EDGES + e]; }
        else             { src = dst = e - N_EDGES; }
        int pos = atomicAdd(&cursor[dst], 1);
        col[pos] = src;
        return;
    }
    int lane = threadIdx.x & 63, w = threadIdx.x >> 6;
    int row = (b - EB) * 4 + w;
    if (row >= N_NODES) return;
    size_t base = (size_t)row * HC + lane * 4;
    float4 p0 = *(const float4*)&B0[base];
    float4 p1 = *(const float4*)&Cp1[base];
    float4 s = make_float4(p0.x + p1.x, p0.y + p1.y, p0.z + p1.z, p0.w + p1.w);
    *(float4*)&B0[base] = s;
    int head = lane >> 4;
    int cw = (lane & 15) * 4;
    float ps = s.x * as_w[head * 64 + cw + 0] + s.y * as_w[head * 64 + cw + 1]
             + s.z * as_w[head * 64 + cw + 2] + s.w * as_w[head * 64 + cw + 3];
    float pd = s.x * ad_w[head * 64 + cw + 0] + s.y * ad_w[head * 64 + cw + 1]
             + s.z * ad_w[head * 64 + cw + 2] + s.w * ad_w[head * 64 + cw + 3];
    #pragma unroll
    for (int o = 1; o < 16; o <<= 1) {
        ps += __shfl_xor(ps, o, 64);
        pd += __shfl_xor(pd, o, 64);
    }
    if ((lane & 15) == 0) {
        als[row * 4 + head] = ps;
        ald[row * 4 + head] = pd;
    }
}

// ======== fused attention-logit epilogue (used by gemm_mfma) ========
#define AL_EPILOGUE()                                                              \
    {                                                                              \
        float asv[NF], adv[NF];                                                    \
        _Pragma("unroll")                                                          \
        for (int j = 0; j < NF; ++j) {                                             \
            int col = bn + wn * SN + j * 16 + (lane & 15);                         \
            asv[j] = as_w[col];                                                    \
            adv[j] = ad_w[col];                                                    \
        }                                                                          \
        float* s_as = (float*)smem;          /* [2][BM] */                         \
        float* s_ad = (float*)smem + 2 * BM;                                       \
        _Pragma("unroll")                                                          \
        for (int i = 0; i < MF; ++i) {                                             \
            _Pragma("unroll")                                                      \
            for (int rr = 0; rr < 4; ++rr) {                                       \
                float ps = 0.f, pd = 0.f;                                          \
                _Pragma("unroll")                                                  \
                for (int j = 0; j < NF; ++j) {                                     \
                    ps += acc[i][j][rr] * asv[j];                                  \
                    pd += acc[i][j][rr] * adv[j];                                  \
                }                                                                  \
                _Pragma("unroll")                                                  \
                for (int o = 1; o < 16; o <<= 1) {                                 \
                    ps += __shfl_xor(ps, o, 64);                                   \
                    pd += __shfl_xor(pd, o, 64);                                   \
                }                                                                  \
                if ((lane & 15) == 0) {                                            \
                    int rl = wm * SM + i * 16 + (lane >> 4) * 4 + rr;              \
                    s_as[wn * BM + rl] = ps;                                       \
                    s_ad[wn * BM + rl] = pd;                                       \
                }                                                                  \
            }                                                                      \
        }                                                                          \
        __syncthreads();                                                           \
        if (t < BM) {                                                              \
            int row = bm + t;                                                      \
            if (row < M) {                                                         \
                int hb = bn >> 6;                                                  \
                als[row * H + hb] = s_as[t] + s_as[BM + t];                        \
                ald[row * H + hb] = s_ad[t] + s_ad[BM + t];                        \
            }                                                                      \
        }                                                                          \
    }

// ---------------- split-bf16 MFMA GEMM (bf16 A), BK=64, fused al ----------------
template<int BMT, int GY, int H>
__launch_bounds__(256)
__global__ void gemm_mfma(const ushort_t* __restrict__ Ah, const ushort_t* __restrict__ Al,
                          const ushort_t* __restrict__ BTh, const ushort_t* __restrict__ BTl,
                          float* __restrict__ C, const float* __restrict__ as_w,
                          const float* __restrict__ ad_w, float* __restrict__ als,
                          float* __restrict__ ald, int M, int K, int NT) {
    constexpr int BM = BMT, BN = 64, SM = BM / 2, SN = 32, MF = SM / 16, NF = 2;
    constexpr int AQ = BM / 64;
    constexpr int ASZ = BM * 64;
    __shared__ __align__(16) char smem[4 * ASZ + 16384];

    const int t = threadIdx.x, lane = t & 63, w = t >> 6;
    const int wm = w >> 1, wn = w & 1;
    const int nwg = gridDim.x;
    const int id = blockIdx.x;
    const int q = nwg >> 3, r = nwg & 7;
    const int xcd = id & 7, idx = id >> 3;
    const int logical = (xcd < r ? xcd * (q + 1) : r * (q + 1) + (xcd - r) * q) + idx;
    const int bm = (logical / GY) * BM, bn = (logical % GY) * BN;
    const int gchunk = ((lane & 3) ^ ((lane >> 3) & 3)) * 16;

    size_t gA[AQ]; int lA[AQ];
    #pragma unroll
    for (int qq = 0; qq < AQ; ++qq) {
        int inst = w * AQ + qq;
        int arow = inst * 16 + (lane >> 2);
        int grow = min(bm + arow, M - 1);
        gA[qq] = (size_t)grow * K * 2 + gchunk;
        lA[qq] = inst * 1024;
    }
    const int brow = w * 16 + (lane >> 2);
    const size_t gB = (size_t)(bn + brow) * K * 2 + gchunk;
    const int lB = w * 1024;

    const char* Ahb = (const char*)Ah;
    const char* Alb = (const char*)Al;
    const char* Bhb = (const char*)BTh;
    const char* Blb = (const char*)BTl;
    const int c16 = (lane >> 4);
    const int NTs = K / 64;

    f32x4 acc[MF][NF];
    #pragma unroll
    for (int i = 0; i < MF; ++i)
        #pragma unroll
        for (int j = 0; j < NF; ++j) acc[i][j] = (f32x4){0.f, 0.f, 0.f, 0.f};

    for (int ts = 0; ts < NTs; ++ts) {
        size_t kb = (size_t)ts * 128;
        #pragma unroll
        for (int kc = 0; kc < 2; ++kc) {
            #pragma unroll
            for (int qq = 0; qq < AQ; ++qq) {
                GLOAD16(Ahb + gA[qq] + kb + kc * 64, smem + kc * ASZ + lA[qq]);
                GLOAD16(Alb + gA[qq] + kb + kc * 64, smem + 2 * ASZ + kc * ASZ + lA[qq]);
            }
            GLOAD16(Bhb + gB + kb + kc * 64, smem + 4 * ASZ + kc * 4096 + lB);
            GLOAD16(Blb + gB + kb + kc * 64, smem + 4 * ASZ + 8192 + kc * 4096 + lB);
        }
        __syncthreads();
        #pragma unroll
        for (int kc = 0; kc < 2; ++kc) {
            short8 afh[MF], afl[MF], bfh[NF], bfl[NF];
            #pragma unroll
            for (int i = 0; i < MF; ++i) {
                int row = wm * SM + i * 16 + (lane & 15);
                int off = row * 64 + ((c16 ^ ((row >> 1) & 3)) * 16);
                afh[i] = *(const short8*)(smem + kc * ASZ + off);
                afl[i] = *(const short8*)(smem + 2 * ASZ + kc * ASZ + off);
            }
            #pragma unroll
            for (int j = 0; j < NF; ++j) {
                int row = wn * SN + j * 16 + (lane & 15);
                int off = row * 64 + ((c16 ^ ((row >> 1) & 3)) * 16);
                bfh[j] = *(const short8*)(smem + 4 * ASZ + kc * 4096 + off);
                bfl[j] = *(const short8*)(smem + 4 * ASZ + 8192 + kc * 4096 + off);
            }
            #pragma unroll
            for (int i = 0; i < MF; ++i)
                #pragma unroll
                for (int j = 0; j < NF; ++j) {
                    acc[i][j] = __builtin_amdgcn_mfma_f32_16x16x32_bf16(afh[i], bfh[j], acc[i][j], 0, 0, 0);
                    acc[i][j] = __builtin_amdgcn_mfma_f32_16x16x32_bf16(afh[i], bfl[j], acc[i][j], 0, 0, 0);
                    acc[i][j] = __builtin_amdgcn_mfma_f32_16x16x32_bf16(afl[i], bfh[j], acc[i][j], 0, 0, 0);
                }
        }
        __syncthreads();
    }
    #pragma unroll
    for (int i = 0; i < MF; ++i) {
        int rbase = bm + wm * SM + i * 16 + (lane >> 4) * 4;
        #pragma unroll
        for (int j = 0; j < NF; ++j) {
            int col = bn + wn * SN + j * 16 + (lane & 15);
            #pragma unroll
            for (int rr = 0; rr < 4; ++rr)
                if (rbase + rr < M) C[(size_t)(rbase + rr) * NT + col] = acc[i][j][rr];
        }
    }
    AL_EPILOGUE()
}

// ---------------- agg v6: fused per-head softmax + channel-sliced gather ----------------
template<int CT, int CW, int H, bool RELU, bool SPLIT, bool CLS>
__launch_bounds__(256)
__global__ void agg_v6(const float* __restrict__ h, const float* __restrict__ als,
                       const float* __restrict__ ald,
                       const int* __restrict__ row_ptr, const int* __restrict__ col,
                       const float* __restrict__ bias,
                       ushort_t* __restrict__ oh, ushort_t* __restrict__ ol,
                       float* __restrict__ of,
                       const float* __restrict__ wc, const float* __restrict__ bc,
                       float* __restrict__ cls_out) {
    constexpr int NS  = CT / CW;
    constexpr int LPT = CW / 4;
    constexpr int TPW = 64 / LPT;
    static_assert(NS == H, "slice==head mapping");
    __shared__ int   s_src[4][64];
    __shared__ float s_alp[4][64];
    const int nwg = gridDim.x;
    const int q = nwg >> 3;
    int id = blockIdx.x;
    int logical = (id & 7) * q + (id >> 3);
    int slice = logical / (N_NODES / 4);
    int g = logical - slice * (N_NODES / 4);
    int lane = threadIdx.x & 63, w = threadIdx.x >> 6;
    int dst = g * 4 + w;
    int beg = row_ptr[dst], deg = row_ptr[dst + 1] - beg;
    int team = lane / LPT;
    int cc = (lane & (LPT - 1)) * 4;

    const int*   colP = col + beg;
    const float* hS   = h + slice * CW + cc;
    float ad = ald[dst * H + slice];

    // ---- pass A: per-head softmax stats ----
    float m = -1e30f, den = 0.f;
    for (int base = 0; base < deg; base += 64) {
        int i = base + lane;
        if (i < deg) {
            float e = als[colP[i] * H + slice] + ad;
            e = (e > 0.f) ? e : 0.2f * e;
            float nm = fmaxf(m, e);
            den = den * __expf(m - nm) + __expf(e - nm);
            m = nm;
        }
    }
    #pragma unroll
    for (int off = 1; off < 64; off <<= 1) {
        float mo = __shfl_xor(m, off, 64);
        float dn = __shfl_xor(den, off, 64);
        float nm = fmaxf(m, mo);
        den = den * __expf(m - nm) + dn * __expf(mo - nm);
        m = nm;
    }
    float rden = 1.f / (den + 1e-16f);

    // ---- pass B: alpha inline to LDS, 4-deep team gather ----
    float4 a0v = make_float4(0.f, 0.f, 0.f, 0.f);
    float4 a1v = make_float4(0.f, 0.f, 0.f, 0.f);
    float4 a2v = make_float4(0.f, 0.f, 0.f, 0.f);
    float4 a3v = make_float4(0.f, 0.f, 0.f, 0.f);
    for (int base = 0; base < deg; base += 64) {
        int cnt = min(64, deg - base);
        if (lane < cnt) {
            int src = colP[base + lane];
            s_src[w][lane] = src;
            float e = als[src * H + slice] + ad;
            e = (e > 0.f) ? e : 0.2f * e;
            s_alp[w][lane] = __expf(e - m) * rden;
        }
        int i = team;
        for (; i + 3 * TPW < cnt; i += 4 * TPW) {
            int   s0 = s_src[w][i],           s1 = s_src[w][i + TPW];
            int   s2 = s_src[w][i + 2 * TPW], s3 = s_src[w][i + 3 * TPW];
            float a0 = s_alp[w][i],           a1 = s_alp[w][i + TPW];
            float a2 = s_alp[w][i + 2 * TPW], a3 = s_alp[w][i + 3 * TPW];
            float4 h0 = *(const float4*)&hS[s0 * CT];
            float4 h1 = *(const float4*)&hS[s1 * CT];
            float4 h2 = *(const float4*)&hS[s2 * CT];
            float4 h3 = *(const float4*)&hS[s3 * CT];
            a0v.x += a0 * h0.x; a0v.y += a0 * h0.y; a0v.z += a0 * h0.z; a0v.w += a0 * h0.w;
            a1v.x += a1 * h1.x; a1v.y += a1 * h1.y; a1v.z += a1 * h1.z; a1v.w += a1 * h1.w;
            a2v.x += a2 * h2.x; a2v.y += a2 * h2.y; a2v.z += a2 * h2.z; a2v.w += a2 * h2.w;
            a3v.x += a3 * h3.x; a3v.y += a3 * h3.y; a3v.z += a3 * h3.z; a3v.w += a3 * h3.w;
        }
        for (; i < cnt; i += TPW) {
            int   s0 = s_src[w][i];
            float a0 = s_alp[w][i];
            float4 h0 = *(const float4*)&hS[s0 * CT];
            a0v.x += a0 * h0.x; a0v.y += a0 * h0.y; a0v.z += a0 * h0.z; a0v.w += a0 * h0.w;
        }
    }
    float4 acc = make_float4((a0v.x + a1v.x) + (a2v.x + a3v.x),
                             (a0v.y + a1v.y) + (a2v.y + a3v.y),
                             (a0v.z + a1v.z) + (a2v.z + a3v.z),
                             (a0v.w + a1v.w) + (a2v.w + a3v.w));
    #pragma unroll
    for (int off = LPT; off < 64; off <<= 1) {
        acc.x += __shfl_xor(acc.x, off, 64);
        acc.y += __shfl_xor(acc.y, off, 64);
        acc.z += __shfl_xor(acc.z, off, 64);
        acc.w += __shfl_xor(acc.w, off, 64);
    }
    if (team == 0) {
        int ch = slice * CW + cc;
        float4 bv = *(const float4*)&bias[ch];
        float v0 = acc.x + bv.x, v1 = acc.y + bv.y, v2 = acc.z + bv.z, v3 = acc.w + bv.w;
        if (RELU) {
            v0 = fmaxf(v0, 0.f); v1 = fmaxf(v1, 0.f);
            v2 = fmaxf(v2, 0.f); v3 = fmaxf(v3, 0.f);
        }
        if (CLS) {
            float ps[NC];
            #pragma unroll
            for (int k = 0; k < NC; ++k)
                ps[k] = v0 * wc[(cc + 0) * NC + k] + v1 * wc[(cc + 1) * NC + k]
                      + v2 * wc[(cc + 2) * NC + k] + v3 * wc[(cc + 3) * NC + k];
            #pragma unroll
            for (int o = 1; o < 16; o <<= 1)
                #pragma unroll
                for (int k = 0; k < NC; ++k) ps[k] += __shfl_xor(ps[k], o, 64);
            if (lane == 0) {
                #pragma unroll
                for (int k = 0; k < NC; ++k) cls_out[(size_t)dst * NC + k] = ps[k] + bc[k];
            }
        } else {
            size_t idx = (size_t)dst * CT + ch;
            if (SPLIT) {
                ushort4 h4, l4;
                h4.x = f2bf(v0); l4.x = f2bf(v0 - bf2f(h4.x));
                h4.y = f2bf(v1); l4.y = f2bf(v1 - bf2f(h4.y));
                h4.z = f2bf(v2); l4.z = f2bf(v2 - bf2f(h4.z));
                h4.w = f2bf(v3); l4.w = f2bf(v3 - bf2f(h4.w));
                *(ushort4*)&oh[idx] = h4;
                *(ushort4*)&ol[idx] = l4;
            } else {
                *(float4*)&of[idx] = make_float4(v0, v1, v2, v3);
            }
        }
    }
}

extern "C" void kernel_launch(void* const* d_in, const int* in_sizes, int n_in,
                              void* d_out, int out_size, void* d_ws, size_t ws_size,
                              hipStream_t stream) {
    const float* x   = (const float*)d_in[0];
    const int*   ei  = (const int*)d_in[1];
    const float* w1  = (const float*)d_in[2];
    const float* as1 = (const float*)d_in[3];
    const float* ad1 = (const float*)d_in[4];
    const float* b1  = (const float*)d_in[5];
    const float* w2  = (const float*)d_in[6];
    const float* as2 = (const float*)d_in[7];
    const float* ad2 = (const float*)d_in[8];
    const float* b2  = (const float*)d_in[9];
    const float* w3  = (const float*)d_in[10];
    const float* as3 = (const float*)d_in[11];
    const float* ad3 = (const float*)d_in[12];
    const float* b3  = (const float*)d_in[13];
    const float* wc  = (const float*)d_in[14];
    const float* bc  = (const float*)d_in[15];
    float* out = (float*)d_out;

    char* ws = (char*)d_ws;
    size_t off = 0;
    auto alloc = [&](size_t bytes) -> char* {
        char* p = ws + off;
        off = (off + bytes + 255) & ~(size_t)255;
        return p;
    };

    int* counts  = (int*)alloc(N_NODES * 4);
    int* cursor  = (int*)alloc(N_NODES * 4);
    int* row_ptr = (int*)alloc((N_NODES + 1) * 4);
    int* colidx  = (int*)alloc(ET * 4);
    float* als   = (float*)alloc(N_NODES * 4 * 4);
    float* ald   = (float*)alloc(N_NODES * 4 * 4);
    float* B0    = (float*)alloc((size_t)N_NODES * HC * 4);
    float* Cp1   = (float*)alloc((size_t)N_NODES * HC * 4);

    ushort_t* w1Th = (ushort_t*)alloc((size_t)F_IN * HC * 2);
    ushort_t* w1Tl = (ushort_t*)alloc((size_t)F_IN * HC * 2);
    ushort_t* w2Th = (ushort_t*)alloc((size_t)HC * HC * 2);
    ushort_t* w2Tl = (ushort_t*)alloc((size_t)HC * HC * 2);
    ushort_t* w3Th = (ushort_t*)alloc((size_t)HC * 64 * 2);
    ushort_t* w3Tl = (ushort_t*)alloc((size_t)HC * 64 * 2);
    ushort_t* B1h  = (ushort_t*)alloc((size_t)N_NODES * HC * 2);
    ushort_t* B1l  = (ushort_t*)alloc((size_t)N_NODES * HC * 2);

    const int EB = (ET + 255) / 256;                         // 1329
    const int PREP = EB + F_IN * HC / 256 + HC * HC / 256 + HC * 64 / 256;  // 2673
    const int nwg128 = ((N_NODES + 127) / 128) * (HC / 64);  // 628
    const int nwgG = 2 * nwg128;                             // 1256
    const int nblk_dst = N_NODES / 4;                        // 5000

    // ---- D1: all weight splits + edge count ----
    hipMemsetAsync(counts, 0, N_NODES * sizeof(int), stream);
    prep_kernel<<<PREP, 256, 0, stream>>>(ei, counts, w1, w1Th, w1Tl,
                                          w2, w2Th, w2Tl, w3, w3Th, w3Tl);
    // ---- scan (standalone, proven) ----
    scan_kernel<<<1, 1024, 0, stream>>>(counts, row_ptr, cursor);
    // ---- gemm1 standalone (proven 55 us) ----
    gemm_f32a_ks<4><<<nwgG, 256, 0, stream>>>(x, w1Th, w1Tl, B0, Cp1, N_NODES, F_IN, HC);
    // ---- D3: scatter || reduce+al (proven fusion) ----
    d3_scatter_reduce<<<EB + nblk_dst, 256, 0, stream>>>(
        ei, cursor, colidx, B0, Cp1, as1, ad1, als, ald);
    // ---- layer 1 agg ----
    agg_v6<256, 64, 4, true, true, false><<<4 * nblk_dst, 256, 0, stream>>>(
        B0, als, ald, row_ptr, colidx, b1, B1h, B1l, nullptr, nullptr, nullptr, nullptr);
    // ---- layer 2 ----
    gemm_mfma<128, 4, 4><<<nwg128, 256, 0, stream>>>(B1h, B1l, w2Th, w2Tl, B0, as2, ad2,
                                                     als, ald, N_NODES, HC, HC);
    agg_v6<256, 64, 4, true, true, false><<<4 * nblk_dst, 256, 0, stream>>>(
        B0, als, ald, row_ptr, colidx, b2, B1h, B1l, nullptr, nullptr, nullptr, nullptr);
    // ---- layer 3 (H=1, C=64) + fused classifier ----
    const int nwg3 = (N_NODES + 63) / 64;                    // 313
    gemm_mfma<64, 1, 1><<<nwg3, 256, 0, stream>>>(B1h, B1l, w3Th, w3Tl, B0, as3, ad3,
                                                  als, ald, N_NODES, HC, 64);
    agg_v6<64, 64, 1, false, false, true><<<nblk_dst, 256, 0, stream>>>(
        B0, als, ald, row_ptr, colidx, b3, nullptr, nullptr, nullptr, wc, bc, out);
}